// Round 1
// baseline (835.130 us; speedup 1.0000x reference)
//
#include <hip/hip_runtime.h>
#include <hip/hip_bf16.h>
#include <stdint.h>

// ---------------------------------------------------------------------------
// bf16 MFMA GEMM pipeline for the 2-layer trunk + 128-head byte predictors.
// All GEMMs: C = A @ B^T-layout-B, A [M][K] row-major bf16, BT [N][K] row-major
// bf16, fp32 accum via v_mfma_f32_16x16x32_bf16, 128x128 tile, BK=32,
// global_load_lds width-16 staging (m97 structure).
// ---------------------------------------------------------------------------

typedef __bf16 bf16x8 __attribute__((ext_vector_type(8)));
typedef float  floatx4 __attribute__((ext_vector_type(4)));

typedef __attribute__((address_space(1))) void as1_void;
typedef __attribute__((address_space(3))) void as3_void;

__device__ __forceinline__ void gld_lds16(const void* g, void* l) {
    // 16B per lane, LDS dest = wave-uniform base + lane*16
    __builtin_amdgcn_global_load_lds((as1_void*)g, (as3_void*)l, 16, 0, 0);
}

__device__ __forceinline__ short f2bf(float f) {
    __hip_bfloat16 h = __float2bfloat16(f);
    short s;
    __builtin_memcpy(&s, &h, 2);
    return s;
}

// ---------------------------------------------------------------------------
// MODE 0: out = relu((acc + b - mean)*gamma*rsqrt(var+eps) + beta) -> bf16
// MODE 1: out = relu(acc + bias) -> bf16
// MODE 2: out = acc + bias -> fp32
// ---------------------------------------------------------------------------
template <int MODE, typename OutT>
__global__ __launch_bounds__(256, 2)
void gemm_bt(const short* __restrict__ A, int lda, long aBatch,
             const short* __restrict__ B, int ldb, long bBatch,
             OutT* __restrict__ C, int ldc, long cBatch,
             int K, int ntilesN,
             const float* __restrict__ p0, const float* __restrict__ p1,
             const float* __restrict__ p2, const float* __restrict__ p3,
             const float* __restrict__ p4, int pBatch)
{
    __shared__ short As[128 * 32];
    __shared__ short Bs[128 * 32];

    const int tid  = threadIdx.x;
    const int w    = tid >> 6;     // wave 0..3
    const int l    = tid & 63;
    const int head = blockIdx.y;
    const int mt   = blockIdx.x / ntilesN;
    const int nt   = blockIdx.x % ntilesN;
    const int m0   = mt * 128;
    const int n0   = nt * 128;

    A += (long)head * aBatch;
    B += (long)head * bBatch;
    C += (long)head * cBatch;
    const float* pb = p0 + (long)head * pBatch;

    const int wm   = (w >> 1) * 64;   // wave M offset in tile
    const int wn   = (w & 1) * 64;    // wave N offset in tile
    const int lrow = l & 15;
    const int lk   = (l >> 4) * 8;

    floatx4 acc[4][4] = {};

    // staging: per wave-round, 64 lanes x 16B = 16 rows x 32 bf16
    const int srow = l >> 2;          // row within 16-row chunk
    const int scol = (l & 3) * 8;     // k offset (elements)
    const short* Ag = A + (long)(m0 + w * 16 + srow) * lda + scol;
    const short* Bg = B + (long)(n0 + w * 16 + srow) * ldb + scol;
    const long a64 = (long)64 * lda;
    const long b64 = (long)64 * ldb;
    short* AsW0 = &As[(w * 16) * 32];
    short* AsW1 = &As[(64 + w * 16) * 32];
    short* BsW0 = &Bs[(w * 16) * 32];
    short* BsW1 = &Bs[(64 + w * 16) * 32];

    for (int k0 = 0; k0 < K; k0 += 32) {
        gld_lds16(Ag + k0,       AsW0);
        gld_lds16(Ag + a64 + k0, AsW1);
        gld_lds16(Bg + k0,       BsW0);
        gld_lds16(Bg + b64 + k0, BsW1);
        __syncthreads();

        bf16x8 af[4], bfr[4];
#pragma unroll
        for (int i = 0; i < 4; ++i)
            af[i] = *(const bf16x8*)&As[(wm + i * 16 + lrow) * 32 + lk];
#pragma unroll
        for (int j = 0; j < 4; ++j)
            bfr[j] = *(const bf16x8*)&Bs[(wn + j * 16 + lrow) * 32 + lk];

#pragma unroll
        for (int i = 0; i < 4; ++i)
#pragma unroll
            for (int j = 0; j < 4; ++j)
                acc[i][j] = __builtin_amdgcn_mfma_f32_16x16x32_bf16(
                    af[i], bfr[j], acc[i][j], 0, 0, 0);
        __syncthreads();
    }

    // epilogue: D lane l holds rows (l>>4)*4+r, col l&15 of each 16x16 subtile
    const int erow = (l >> 4) * 4;
    const int ecol = l & 15;
#pragma unroll
    for (int j = 0; j < 4; ++j) {
        const int nj = n0 + wn + j * 16 + ecol;
        float scale = 1.f, shift;
        if constexpr (MODE == 0) {
            const float s = p1[nj] * rsqrtf(p4[nj] + 1e-5f);
            scale = s;
            shift = (pb[nj] - p3[nj]) * s + p2[nj];
        } else {
            shift = pb[nj];
        }
#pragma unroll
        for (int i = 0; i < 4; ++i) {
            const long mi = m0 + wm + i * 16 + erow;
#pragma unroll
            for (int r = 0; r < 4; ++r) {
                float v = acc[i][j][r] * scale + shift;
                if constexpr (MODE != 2) v = fmaxf(v, 0.f);
                const long idx = (mi + r) * (long)ldc + nj;
                if constexpr (sizeof(OutT) == 2) C[idx] = (OutT)f2bf(v);
                else                             C[idx] = (OutT)v;
            }
        }
    }
}

// ---------------------------------------------------------------------------
// fp32 [R][C] -> bf16 [C][Rpad] transpose (zero-pad rows R..Rpad), batched
// ---------------------------------------------------------------------------
__global__ void transpose_f32_bf16(const float* __restrict__ in, short* __restrict__ out,
                                   int R, int C, int Rpad, long inBatch, long outBatch)
{
    __shared__ float tile[32][33];
    in  += (long)blockIdx.z * inBatch;
    out += (long)blockIdx.z * outBatch;
    const int c0 = blockIdx.x * 32;   // in-col tile
    const int r0 = blockIdx.y * 32;   // in-row tile (padded space)
    const int tx = threadIdx.x, ty = threadIdx.y;   // 32 x 8
#pragma unroll
    for (int rr = 0; rr < 4; ++rr) {
        const int r = r0 + ty + rr * 8;
        float v = 0.f;
        if (r < R) v = in[(long)r * C + c0 + tx];
        tile[ty + rr * 8][tx] = v;
    }
    __syncthreads();
#pragma unroll
    for (int rr = 0; rr < 4; ++rr) {
        const int oc = ty + rr * 8;
        out[(long)(c0 + oc) * Rpad + r0 + tx] = f2bf(tile[tx][oc]);
    }
}

// fp32 [R][C] -> bf16 [R][Cpad], zero-padded cols
__global__ void pad_convert(const float* __restrict__ in, short* __restrict__ out,
                            int C, int Cpad, int total)
{
    const int idx = blockIdx.x * 256 + threadIdx.x;
    if (idx >= total) return;
    const int r = idx / Cpad, c = idx % Cpad;
    out[idx] = f2bf(c < C ? in[(long)r * C + c] : 0.f);
}

// ---------------------------------------------------------------------------

extern "C" void kernel_launch(void* const* d_in, const int* in_sizes, int n_in,
                              void* d_out, int out_size, void* d_ws, size_t ws_size,
                              hipStream_t stream)
{
    const float* x   = (const float*)d_in[0];
    const float* W0  = (const float*)d_in[1];
    const float* b0  = (const float*)d_in[2];
    const float* g0  = (const float*)d_in[3];
    const float* be0 = (const float*)d_in[4];
    const float* m0  = (const float*)d_in[5];
    const float* v0  = (const float*)d_in[6];
    const float* W1  = (const float*)d_in[7];
    const float* b1  = (const float*)d_in[8];
    const float* g1  = (const float*)d_in[9];
    const float* be1 = (const float*)d_in[10];
    const float* m1  = (const float*)d_in[11];
    const float* v1  = (const float*)d_in[12];
    const float* HW1 = (const float*)d_in[13];
    const float* Hb1 = (const float*)d_in[14];
    const float* HW2 = (const float*)d_in[15];
    const float* Hb2 = (const float*)d_in[16];
    float* out = (float*)d_out;

    char* ws = (char*)d_ws;
    size_t off = 0;
    short* xb   = (short*)(ws + off); off += (size_t)1024 * 224 * 2;        // x bf16, K-pad
    short* W0T  = (short*)(ws + off); off += (size_t)2048 * 224 * 2;        // [2048][224]
    short* W1T  = (short*)(ws + off); off += (size_t)1024 * 2048 * 2;       // [1024][2048]
    short* HW1T = (short*)(ws + off); off += (size_t)128 * 512 * 1024 * 2;  // [128][512][1024]
    short* HW2T = (short*)(ws + off); off += (size_t)128 * 256 * 512 * 2;   // [128][256][512]
    short* h    = (short*)(ws + off); off += (size_t)1024 * 2048 * 2;       // trunk act 1
    short* fts  = (short*)(ws + off); off += (size_t)1024 * 1024 * 2;       // trunk act 2
    short* z    = (short*)(ws + off); off += (size_t)1024 * 128 * 512 * 2;  // head hidden
    // total ~300 MB

    const dim3 tb(32, 8);

    // weight/activation conversion to bf16 (B^T layout for GEMM B-operands)
    pad_convert<<<dim3((1024 * 224) / 256), dim3(256), 0, stream>>>(x, xb, 200, 224, 1024 * 224);
    transpose_f32_bf16<<<dim3(64, 7, 1),    tb, 0, stream>>>(W0,  W0T,  200,  2048, 224,  0, 0);
    transpose_f32_bf16<<<dim3(32, 64, 1),   tb, 0, stream>>>(W1,  W1T,  2048, 1024, 2048, 0, 0);
    transpose_f32_bf16<<<dim3(16, 32, 128), tb, 0, stream>>>(HW1, HW1T, 1024, 512,  1024,
                                                             (long)1024 * 512, (long)512 * 1024);
    transpose_f32_bf16<<<dim3(8, 16, 128),  tb, 0, stream>>>(HW2, HW2T, 512,  256,  512,
                                                             (long)512 * 256, (long)256 * 512);

    // trunk: h = relu(BN0(x@W0 + b0))   M=1024 N=2048 K=224
    gemm_bt<0, short><<<dim3(8 * 16, 1), dim3(256), 0, stream>>>(
        xb, 224, 0, W0T, 224, 0, h, 2048, 0, 224, 16, b0, g0, be0, m0, v0, 0);
    // trunk: feats = relu(BN1(h@W1 + b1))   M=1024 N=1024 K=2048
    gemm_bt<0, short><<<dim3(8 * 8, 1), dim3(256), 0, stream>>>(
        h, 2048, 0, W1T, 2048, 0, fts, 1024, 0, 2048, 8, b1, g1, be1, m1, v1, 0);
    // heads layer 1: z = relu(feats@HW1[n] + Hb1[n])   per head M=1024 N=512 K=1024
    gemm_bt<1, short><<<dim3(8 * 4, 128), dim3(256), 0, stream>>>(
        fts, 1024, 0, HW1T, 1024, (long)512 * 1024, z, 128 * 512, 512,
        1024, 4, Hb1, nullptr, nullptr, nullptr, nullptr, 512);
    // heads layer 2: out = z@HW2[n] + Hb2[n]   per head M=1024 N=256 K=512
    gemm_bt<2, float><<<dim3(8 * 2, 128), dim3(256), 0, stream>>>(
        z, 128 * 512, 512, HW2T, 512, (long)256 * 512, out, 128 * 256, 256,
        512, 2, Hb2, nullptr, nullptr, nullptr, nullptr, 256);

    (void)in_sizes; (void)n_in; (void)out_size; (void)ws_size;
}

// Round 3
// 811.199 us; speedup vs baseline: 1.0295x; 1.0295x over previous
//
#include <hip/hip_runtime.h>
#include <hip/hip_bf16.h>
#include <stdint.h>

// ---------------------------------------------------------------------------
// bf16 MFMA GEMM pipeline for the 2-layer trunk + 128-head byte predictors.
// R2b: fast vectorized fp32->bf16 transpose (4x4 in-register micro-transpose,
// b64 LDS writes, 16B global stores); compile fix for ext-vector element
// address-of. GEMMs unchanged from R1.
// ---------------------------------------------------------------------------

typedef __bf16 bf16x8 __attribute__((ext_vector_type(8)));
typedef float  floatx4 __attribute__((ext_vector_type(4)));
typedef unsigned short ushortx4 __attribute__((ext_vector_type(4)));
typedef unsigned short ushortx8 __attribute__((ext_vector_type(8)));

typedef __attribute__((address_space(1))) void as1_void;
typedef __attribute__((address_space(3))) void as3_void;

__device__ __forceinline__ void gld_lds16(const void* g, void* l) {
    __builtin_amdgcn_global_load_lds((as1_void*)g, (as3_void*)l, 16, 0, 0);
}

__device__ __forceinline__ unsigned short f2bf(float f) {
    __hip_bfloat16 h = __float2bfloat16(f);
    unsigned short s;
    __builtin_memcpy(&s, &h, 2);
    return s;
}

// ---------------------------------------------------------------------------
// MODE 0: out = relu((acc + b - mean)*gamma*rsqrt(var+eps) + beta) -> bf16
// MODE 1: out = relu(acc + bias) -> bf16
// MODE 2: out = acc + bias -> fp32
// ---------------------------------------------------------------------------
template <int MODE, typename OutT>
__global__ __launch_bounds__(256, 2)
void gemm_bt(const short* __restrict__ A, int lda, long aBatch,
             const short* __restrict__ B, int ldb, long bBatch,
             OutT* __restrict__ C, int ldc, long cBatch,
             int K, int ntilesN,
             const float* __restrict__ p0, const float* __restrict__ p1,
             const float* __restrict__ p2, const float* __restrict__ p3,
             const float* __restrict__ p4, int pBatch)
{
    __shared__ short As[128 * 32];
    __shared__ short Bs[128 * 32];

    const int tid  = threadIdx.x;
    const int w    = tid >> 6;
    const int l    = tid & 63;
    const int head = blockIdx.y;
    const int mt   = blockIdx.x / ntilesN;
    const int nt   = blockIdx.x % ntilesN;
    const int m0   = mt * 128;
    const int n0   = nt * 128;

    A += (long)head * aBatch;
    B += (long)head * bBatch;
    C += (long)head * cBatch;
    const float* pb = p0 + (long)head * pBatch;

    const int wm   = (w >> 1) * 64;
    const int wn   = (w & 1) * 64;
    const int lrow = l & 15;
    const int lk   = (l >> 4) * 8;

    floatx4 acc[4][4] = {};

    const int srow = l >> 2;
    const int scol = (l & 3) * 8;
    const short* Ag = A + (long)(m0 + w * 16 + srow) * lda + scol;
    const short* Bg = B + (long)(n0 + w * 16 + srow) * ldb + scol;
    const long a64 = (long)64 * lda;
    const long b64 = (long)64 * ldb;
    short* AsW0 = &As[(w * 16) * 32];
    short* AsW1 = &As[(64 + w * 16) * 32];
    short* BsW0 = &Bs[(w * 16) * 32];
    short* BsW1 = &Bs[(64 + w * 16) * 32];

    for (int k0 = 0; k0 < K; k0 += 32) {
        gld_lds16(Ag + k0,       AsW0);
        gld_lds16(Ag + a64 + k0, AsW1);
        gld_lds16(Bg + k0,       BsW0);
        gld_lds16(Bg + b64 + k0, BsW1);
        __syncthreads();

        bf16x8 af[4], bfr[4];
#pragma unroll
        for (int i = 0; i < 4; ++i)
            af[i] = *(const bf16x8*)&As[(wm + i * 16 + lrow) * 32 + lk];
#pragma unroll
        for (int j = 0; j < 4; ++j)
            bfr[j] = *(const bf16x8*)&Bs[(wn + j * 16 + lrow) * 32 + lk];

#pragma unroll
        for (int i = 0; i < 4; ++i)
#pragma unroll
            for (int j = 0; j < 4; ++j)
                acc[i][j] = __builtin_amdgcn_mfma_f32_16x16x32_bf16(
                    af[i], bfr[j], acc[i][j], 0, 0, 0);
        __syncthreads();
    }

    const int erow = (l >> 4) * 4;
    const int ecol = l & 15;
#pragma unroll
    for (int j = 0; j < 4; ++j) {
        const int nj = n0 + wn + j * 16 + ecol;
        float scale = 1.f, shift;
        if constexpr (MODE == 0) {
            const float s = p1[nj] * rsqrtf(p4[nj] + 1e-5f);
            scale = s;
            shift = (pb[nj] - p3[nj]) * s + p2[nj];
        } else {
            shift = pb[nj];
        }
#pragma unroll
        for (int i = 0; i < 4; ++i) {
            const long mi = m0 + wm + i * 16 + erow;
#pragma unroll
            for (int r = 0; r < 4; ++r) {
                float v = acc[i][j][r] * scale + shift;
                if constexpr (MODE != 2) v = fmaxf(v, 0.f);
                const long idx = (mi + r) * (long)ldc + nj;
                if constexpr (sizeof(OutT) == 2) C[idx] = (OutT)f2bf(v);
                else                             C[idx] = (OutT)v;
            }
        }
    }
}

// ---------------------------------------------------------------------------
// Fast fp32 [R][C] -> bf16 [C][R] transpose, R and C multiples of 64, batched.
// 64x64 tile per block, 256 threads.
// ---------------------------------------------------------------------------
__global__ __launch_bounds__(256)
void transpose64(const float* __restrict__ in, unsigned short* __restrict__ out,
                 int R, int C, long inBatch, long outBatch)
{
    __shared__ unsigned short lt[64 * 68];
    in  += (long)blockIdx.z * inBatch;
    out += (long)blockIdx.z * outBatch;
    const int c0 = blockIdx.x * 64;   // in-col tile origin
    const int r0 = blockIdx.y * 64;   // in-row tile origin
    const int t  = threadIdx.x;

    // Phase A: float4 loads, 4x4 register transpose, b64 LDS writes
    {
        const int rb = t >> 4;          // 0..15, rows rb*4..+3
        const int cg = (t & 15) * 4;    // cols cg..cg+3
        floatx4 v[4];
#pragma unroll
        for (int i = 0; i < 4; ++i)
            v[i] = *(const floatx4*)&in[(long)(r0 + rb * 4 + i) * C + c0 + cg];
#pragma unroll
        for (int j = 0; j < 4; ++j) {
            ushortx4 col;
#pragma unroll
            for (int i = 0; i < 4; ++i) col[i] = f2bf(v[i][j]);
            *(ushortx4*)&lt[(cg + j) * 68 + rb * 4] = col;
        }
    }
    __syncthreads();

    // Phase B: 2x b64 LDS reads -> one 16B global store per thread-iter
#pragma unroll
    for (int it = 0; it < 2; ++it) {
        const int idx = t + it * 256;   // 0..511
        const int c   = idx >> 3;       // 0..63
        const int rc  = idx & 7;        // 0..7 (8-elem chunk along r)
        ushortx4 lo = *(const ushortx4*)&lt[c * 68 + rc * 8];
        ushortx4 hi = *(const ushortx4*)&lt[c * 68 + rc * 8 + 4];
        ushortx8 o;
        o[0] = lo[0]; o[1] = lo[1]; o[2] = lo[2]; o[3] = lo[3];
        o[4] = hi[0]; o[5] = hi[1]; o[6] = hi[2]; o[7] = hi[3];
        *(ushortx8*)&out[(long)(c0 + c) * R + r0 + rc * 8] = o;
    }
}

// ---------------------------------------------------------------------------
// slow-path transpose (used only for tiny W0 with R=200 -> Rpad=224)
// ---------------------------------------------------------------------------
__global__ void transpose_f32_bf16(const float* __restrict__ in, short* __restrict__ out,
                                   int R, int C, int Rpad, long inBatch, long outBatch)
{
    __shared__ float tile[32][33];
    in  += (long)blockIdx.z * inBatch;
    out += (long)blockIdx.z * outBatch;
    const int c0 = blockIdx.x * 32;
    const int r0 = blockIdx.y * 32;
    const int tx = threadIdx.x, ty = threadIdx.y;
#pragma unroll
    for (int rr = 0; rr < 4; ++rr) {
        const int r = r0 + ty + rr * 8;
        float v = 0.f;
        if (r < R) v = in[(long)r * C + c0 + tx];
        tile[ty + rr * 8][tx] = v;
    }
    __syncthreads();
#pragma unroll
    for (int rr = 0; rr < 4; ++rr) {
        const int oc = ty + rr * 8;
        out[(long)(c0 + oc) * Rpad + r0 + tx] = (short)f2bf(tile[tx][oc]);
    }
}

// fp32 [R][C] -> bf16 [R][Cpad], zero-padded cols
__global__ void pad_convert(const float* __restrict__ in, short* __restrict__ out,
                            int C, int Cpad, int total)
{
    const int idx = blockIdx.x * 256 + threadIdx.x;
    if (idx >= total) return;
    const int r = idx / Cpad, c = idx % Cpad;
    out[idx] = (short)f2bf(c < C ? in[(long)r * C + c] : 0.f);
}

// ---------------------------------------------------------------------------

extern "C" void kernel_launch(void* const* d_in, const int* in_sizes, int n_in,
                              void* d_out, int out_size, void* d_ws, size_t ws_size,
                              hipStream_t stream)
{
    const float* x   = (const float*)d_in[0];
    const float* W0  = (const float*)d_in[1];
    const float* b0  = (const float*)d_in[2];
    const float* g0  = (const float*)d_in[3];
    const float* be0 = (const float*)d_in[4];
    const float* m0  = (const float*)d_in[5];
    const float* v0  = (const float*)d_in[6];
    const float* W1  = (const float*)d_in[7];
    const float* b1  = (const float*)d_in[8];
    const float* g1  = (const float*)d_in[9];
    const float* be1 = (const float*)d_in[10];
    const float* m1  = (const float*)d_in[11];
    const float* v1  = (const float*)d_in[12];
    const float* HW1 = (const float*)d_in[13];
    const float* Hb1 = (const float*)d_in[14];
    const float* HW2 = (const float*)d_in[15];
    const float* Hb2 = (const float*)d_in[16];
    float* out = (float*)d_out;

    char* ws = (char*)d_ws;
    size_t off = 0;
    short* xb   = (short*)(ws + off); off += (size_t)1024 * 224 * 2;
    short* W0T  = (short*)(ws + off); off += (size_t)2048 * 224 * 2;
    short* W1T  = (short*)(ws + off); off += (size_t)1024 * 2048 * 2;
    short* HW1T = (short*)(ws + off); off += (size_t)128 * 512 * 1024 * 2;
    short* HW2T = (short*)(ws + off); off += (size_t)128 * 256 * 512 * 2;
    short* h    = (short*)(ws + off); off += (size_t)1024 * 2048 * 2;
    short* fts  = (short*)(ws + off); off += (size_t)1024 * 1024 * 2;
    short* z    = (short*)(ws + off); off += (size_t)1024 * 128 * 512 * 2;

    // bf16 conversions / transposes
    pad_convert<<<dim3((1024 * 224) / 256), dim3(256), 0, stream>>>(x, xb, 200, 224, 1024 * 224);
    transpose_f32_bf16<<<dim3(64, 7, 1), dim3(32, 8), 0, stream>>>(W0, W0T, 200, 2048, 224, 0, 0);
    // W1 [2048][1024] -> [1024][2048]
    transpose64<<<dim3(16, 32, 1), dim3(256), 0, stream>>>(
        W1, (unsigned short*)W1T, 2048, 1024, 0, 0);
    // HW1 [128][1024][512] -> [128][512][1024]
    transpose64<<<dim3(8, 16, 128), dim3(256), 0, stream>>>(
        HW1, (unsigned short*)HW1T, 1024, 512, (long)1024 * 512, (long)512 * 1024);
    // HW2 [128][512][256] -> [128][256][512]
    transpose64<<<dim3(4, 8, 128), dim3(256), 0, stream>>>(
        HW2, (unsigned short*)HW2T, 512, 256, (long)512 * 256, (long)256 * 512);

    // trunk: h = relu(BN0(x@W0 + b0))   M=1024 N=2048 K=224
    gemm_bt<0, short><<<dim3(8 * 16, 1), dim3(256), 0, stream>>>(
        xb, 224, 0, W0T, 224, 0, h, 2048, 0, 224, 16, b0, g0, be0, m0, v0, 0);
    // trunk: feats = relu(BN1(h@W1 + b1))   M=1024 N=1024 K=2048
    gemm_bt<0, short><<<dim3(8 * 8, 1), dim3(256), 0, stream>>>(
        h, 2048, 0, W1T, 2048, 0, fts, 1024, 0, 2048, 8, b1, g1, be1, m1, v1, 0);
    // heads layer 1: z = relu(feats@HW1[n] + Hb1[n])   per head M=1024 N=512 K=1024
    gemm_bt<1, short><<<dim3(8 * 4, 128), dim3(256), 0, stream>>>(
        fts, 1024, 0, HW1T, 1024, (long)512 * 1024, z, 128 * 512, 512,
        1024, 4, Hb1, nullptr, nullptr, nullptr, nullptr, 512);
    // heads layer 2: out = z@HW2[n] + Hb2[n]   per head M=1024 N=256 K=512
    gemm_bt<2, float><<<dim3(8 * 2, 128), dim3(256), 0, stream>>>(
        z, 128 * 512, 512, HW2T, 512, (long)256 * 512, out, 128 * 256, 256,
        512, 2, Hb2, nullptr, nullptr, nullptr, nullptr, 256);

    (void)in_sizes; (void)n_in; (void)out_size; (void)ws_size;
}